// Round 2
// baseline (2302.243 us; speedup 1.0000x reference)
//
#include <hip/hip_runtime.h>

typedef unsigned int u32;
typedef unsigned short u16;

typedef short bf16x8 __attribute__((ext_vector_type(8)));
typedef float f32x4 __attribute__((ext_vector_type(4)));

#define DD 128
#define DMM 384
#define KNB 20

__device__ __forceinline__ u16 f2b(float f){
  u32 u = __float_as_uint(f);
  u += 0x7fffu + ((u >> 16) & 1u);
  return (u16)(u >> 16);
}
__device__ __forceinline__ float b2f(u32 h){ return __uint_as_float(h << 16); }

// ---------------- prep ----------------
__global__ void zt_kernel(const float* __restrict__ phase, float* __restrict__ zt){
  int d = threadIdx.x;
  if (d < DD) zt[d] = cosf(phase[d]);
}

// src: K x N row-major fp32  ->  dst: N x K row-major bf16
__global__ void tcvt_kernel(const float* __restrict__ src, u16* __restrict__ dst, int K, int N){
  int i = blockIdx.x * 256 + threadIdx.x;
  if (i >= K * N) return;
  int k = i / N, n = i - k * N;
  dst[(size_t)n * K + k] = f2b(src[i]);
}

// ---------------- build K rows: [feat | rel_emb | time_enc] (chunk-local) ----------------
__global__ __launch_bounds__(256) void build_k_kernel(
  const float* __restrict__ node_table,
  const int*   __restrict__ nodes,           // chunk-local base
  const float* __restrict__ feat_override,   // null, or chunk-local rows x 128 fp32
  const float* __restrict__ t_src,           // chunk-local per-b source time
  const float* __restrict__ t_ngh,           // chunk-local per-row neighbor time
  const float* __restrict__ rel,             // chunk-local rows x 3
  const float* __restrict__ relW, const float* __restrict__ relb,
  const float* __restrict__ bfreq, const float* __restrict__ phase,
  u16* __restrict__ kmat, int nrows)
{
  int lr = blockIdx.x * 2 + (threadIdx.x >> 7);
  if (lr >= nrows) return;
  int d = threadIdx.x & 127;
  int b = lr / KNB;
  float f;
  if (feat_override) f = feat_override[(size_t)lr * DD + d];
  else { int nd = nodes[lr]; f = node_table[(size_t)nd * DD + d]; }
  float r0 = rel[(size_t)lr * 3 + 0], r1 = rel[(size_t)lr * 3 + 1], r2 = rel[(size_t)lr * 3 + 2];
  float re = r0 * relW[d] + r1 * relW[DD + d] + r2 * relW[2 * DD + d] + relb[d];
  float dt = t_src[b] - t_ngh[lr];
  float te = cosf(dt * bfreq[d] + phase[d]);
  u16* kr = kmat + (size_t)lr * DMM;
  kr[d] = f2b(f); kr[DD + d] = f2b(re); kr[2 * DD + d] = f2b(te);
}

// ---------------- build q rows: [src | 0 | zt] bf16  (+src fp32) ----------------
__global__ __launch_bounds__(256) void build_q_kernel(
  const float* __restrict__ node_table,
  const int*   __restrict__ src_nodes,       // chunk-local base
  const float* __restrict__ feat_override,   // chunk-local, or null
  const float* __restrict__ zt,
  u16* __restrict__ qmat, float* __restrict__ srcf,
  int nb)
{
  int r = blockIdx.x * 2 + (threadIdx.x >> 7);
  if (r >= nb) return;
  int d = threadIdx.x & 127;
  float s = feat_override ? feat_override[(size_t)r * DD + d]
                          : node_table[(size_t)src_nodes[r] * DD + d];
  size_t q0 = (size_t)r * DMM;
  qmat[q0 + d] = f2b(s); qmat[q0 + DD + d] = 0; qmat[q0 + 2 * DD + d] = f2b(zt[d]);
  srcf[(size_t)r * DD + d] = s;
}

// ---------------- GEMM: C[M,N] = A[M,K] @ BT[N,K]^T (bf16 in, fp32 acc) ----------------
#define SAS 40   // 32 + 8 pad -> 2-way LDS conflicts only, 16B-aligned rows
__global__ __launch_bounds__(256) void gemm_kernel(
  const u16* __restrict__ A, const u16* __restrict__ BT,
  const float* __restrict__ bias,
  float* __restrict__ Cf, u16* __restrict__ Cb,
  int M, int N, int K, int relu)
{
  __shared__ __align__(16) u16 lds[2 * 128 * SAS];
  u16* As = lds; u16* Bs = lds + 128 * SAS;
  int tid = threadIdx.x;
  int lane = tid & 63, w = tid >> 6;
  int wm = w >> 1, wn = w & 1;
  int bm = blockIdx.x, bn = blockIdx.y;
  f32x4 acc[4][4] = {};
  int r0 = tid >> 2;      // 0..63
  int c0 = tid & 3;       // 16B chunk within 32-col k-tile
  const u16* Abase = A + (size_t)(bm * 128) * K;
  const u16* Bbase = BT + (size_t)(bn * 128) * K;
  int rr = lane & 15, kq = lane >> 4;
  for (int kt = 0; kt < K; kt += 32) {
    uint4 a0 = *(const uint4*)(Abase + (size_t)r0 * K + kt + c0 * 8);
    uint4 a1 = *(const uint4*)(Abase + (size_t)(r0 + 64) * K + kt + c0 * 8);
    uint4 b0 = *(const uint4*)(Bbase + (size_t)r0 * K + kt + c0 * 8);
    uint4 b1 = *(const uint4*)(Bbase + (size_t)(r0 + 64) * K + kt + c0 * 8);
    __syncthreads();
    *(uint4*)&As[r0 * SAS + c0 * 8] = a0;
    *(uint4*)&As[(r0 + 64) * SAS + c0 * 8] = a1;
    *(uint4*)&Bs[r0 * SAS + c0 * 8] = b0;
    *(uint4*)&Bs[(r0 + 64) * SAS + c0 * 8] = b1;
    __syncthreads();
    bf16x8 af[4], bf[4];
    #pragma unroll
    for (int i = 0; i < 4; i++) af[i] = *(const bf16x8*)&As[(wm * 64 + i * 16 + rr) * SAS + kq * 8];
    #pragma unroll
    for (int j = 0; j < 4; j++) bf[j] = *(const bf16x8*)&Bs[(wn * 64 + j * 16 + rr) * SAS + kq * 8];
    #pragma unroll
    for (int i = 0; i < 4; i++)
      #pragma unroll
      for (int j = 0; j < 4; j++)
        acc[i][j] = __builtin_amdgcn_mfma_f32_16x16x32_bf16(af[i], bf[j], acc[i][j], 0, 0, 0);
  }
  int drow = lane >> 4, dcol = lane & 15;
  #pragma unroll
  for (int i = 0; i < 4; i++) {
    #pragma unroll
    for (int j = 0; j < 4; j++) {
      int gcol = bn * 128 + wn * 64 + j * 16 + dcol;
      float bia = bias ? bias[gcol] : 0.f;
      #pragma unroll
      for (int r = 0; r < 4; r++) {
        int grow = bm * 128 + wm * 64 + i * 16 + drow * 4 + r;
        float v = acc[i][j][r] + bia;
        if (relu) v = fmaxf(v, 0.f);
        if (Cf) Cf[(size_t)grow * N + gcol] = v;
        else    Cb[(size_t)grow * N + gcol] = f2b(v);
      }
    }
  }
}

// ---------------- attention: one wave per b-row (all chunk-local) ----------------
__global__ __launch_bounds__(64) void attn_kernel(
  const float* __restrict__ qh,     // chunk-local nb x 384 fp32
  const u16*  __restrict__ khvh,    // chunk-local rows x 768 bf16 ([kh|vh])
  const int*  __restrict__ nodes,   // chunk-local base, b*20+n
  u16* __restrict__ attn_o)         // chunk-local nb x 384 bf16
{
  int b = blockIdx.x;
  int lane = threadIdx.x;
  int h = lane >> 5, t = lane & 31;    // head, 32 lanes/head; lane owns 6 dims
  float qv[6];
  const float* qp = qh + (size_t)b * DMM + h * 192 + t * 6;
  #pragma unroll
  for (int j = 0; j < 6; j++) qv[j] = qp[j];
  __shared__ float sc2[2][KNB];
  const float scale = 0.07216878364870323f;   // 1/sqrt(192)
  for (int n = 0; n < KNB; n++) {
    const u32* kp = (const u32*)(khvh + ((size_t)b * KNB + n) * 768 + h * 192);
    u32 u0 = kp[t * 3 + 0], u1 = kp[t * 3 + 1], u2 = kp[t * 3 + 2];
    float ps = qv[0] * b2f(u0 & 0xffffu) + qv[1] * b2f(u0 >> 16)
             + qv[2] * b2f(u1 & 0xffffu) + qv[3] * b2f(u1 >> 16)
             + qv[4] * b2f(u2 & 0xffffu) + qv[5] * b2f(u2 >> 16);
    ps += __shfl_xor(ps, 1);  ps += __shfl_xor(ps, 2);
    ps += __shfl_xor(ps, 4);  ps += __shfl_xor(ps, 8);  ps += __shfl_xor(ps, 16);
    if (t == 0) sc2[h][n] = ps * scale;
  }
  __syncthreads();
  float s[KNB]; float mx = -3.4e38f;
  #pragma unroll
  for (int n = 0; n < KNB; n++) {
    int nd = nodes[(size_t)b * KNB + n];
    float x = (nd == 0) ? -1e10f : sc2[h][n];
    s[n] = x; mx = fmaxf(mx, x);
  }
  float se = 0.f;
  #pragma unroll
  for (int n = 0; n < KNB; n++) { float e = __expf(s[n] - mx); s[n] = e; se += e; }
  float inv = 1.f / se;
  float a6[6] = {0, 0, 0, 0, 0, 0};
  for (int n = 0; n < KNB; n++) {
    float p = s[n] * inv;
    const u32* vp = (const u32*)(khvh + ((size_t)b * KNB + n) * 768 + DMM);
    u32 u0 = vp[lane * 3 + 0], u1 = vp[lane * 3 + 1], u2 = vp[lane * 3 + 2];
    a6[0] += p * b2f(u0 & 0xffffu); a6[1] += p * b2f(u0 >> 16);
    a6[2] += p * b2f(u1 & 0xffffu); a6[3] += p * b2f(u1 >> 16);
    a6[4] += p * b2f(u2 & 0xffffu); a6[5] += p * b2f(u2 >> 16);
  }
  u16* op = attn_o + (size_t)b * DMM + lane * 6;
  #pragma unroll
  for (int j = 0; j < 6; j++) op[j] = f2b(a6[j]);
}

// ---------------- LN(fcx + fcb + q) -> cat = [ln | src] bf16; q rebuilt from srcf/zt ----------------
__global__ __launch_bounds__(256) void ln_kernel(
  const float* __restrict__ fcx, const float* __restrict__ fcb,
  const float* __restrict__ srcf, const float* __restrict__ zt,
  const float* __restrict__ g, const float* __restrict__ bb,
  u16* __restrict__ cat)
{
  int r = blockIdx.x * 4 + (threadIdx.x >> 6);
  int lane = threadIdx.x & 63;
  const float* x = fcx + (size_t)r * DMM;
  float v[6]; float s = 0.f;
  #pragma unroll
  for (int j = 0; j < 6; j++) {
    int c = lane * 6 + j;
    float q = (c < DD) ? srcf[(size_t)r * DD + c] : ((c < 2 * DD) ? 0.f : zt[c - 2 * DD]);
    v[j] = x[c] + fcb[c] + q; s += v[j];
  }
  #pragma unroll
  for (int m = 1; m < 64; m <<= 1) s += __shfl_xor(s, m);
  float mu = s * (1.f / 384.f);
  float vs = 0.f;
  #pragma unroll
  for (int j = 0; j < 6; j++) { float d = v[j] - mu; vs += d * d; }
  #pragma unroll
  for (int m = 1; m < 64; m <<= 1) vs += __shfl_xor(vs, m);
  float rstd = rsqrtf(vs * (1.f / 384.f) + 1e-5f);
  u16* cr = cat + (size_t)r * (DMM + DD);
  #pragma unroll
  for (int j = 0; j < 6; j++) { int c = lane * 6 + j; cr[c] = f2b((v[j] - mu) * rstd * g[c] + bb[c]); }
  #pragma unroll
  for (int j = 0; j < 2; j++) { int c = lane * 2 + j; cr[DMM + c] = f2b(srcf[(size_t)r * DD + c]); }
}

extern "C" void kernel_launch(void* const* d_in, const int* in_sizes, int n_in,
                              void* d_out, int out_size, void* d_ws, size_t ws_size,
                              hipStream_t stream)
{
  (void)in_sizes; (void)n_in; (void)out_size;
  const int B = 1024, K = 20, D = 128, DM = 384;
  const int BKR = B * K;                 // 20480
  const int NC = 16, CB = BKR / NC;      // 1280 b-rows per chunk
  const int CM = CB * K;                 // 25600 k-rows per chunk (mult of 128)

  const int*   src_idx    = (const int*)  d_in[0];
  const float* cut_time   = (const float*)d_in[1];
  const int*   n1_nodes   = (const int*)  d_in[2];
  const float* n1_t       = (const float*)d_in[3];
  const float* n1_rel     = (const float*)d_in[4];
  const int*   n2_nodes   = (const int*)  d_in[5];
  const float* n2_t       = (const float*)d_in[6];
  const float* n2_rel     = (const float*)d_in[7];
  const float* node_table = (const float*)d_in[8];
  const float* bfreq      = (const float*)d_in[9];
  const float* phase      = (const float*)d_in[10];
  const float* relW       = (const float*)d_in[11];
  const float* relb       = (const float*)d_in[12];
  const float* wq         = (const float*)d_in[13];
  const float* wk         = (const float*)d_in[14];
  const float* wv         = (const float*)d_in[15];
  const float* fcW        = (const float*)d_in[16];
  const float* fcb        = (const float*)d_in[17];
  const float* lng        = (const float*)d_in[18];
  const float* lnb        = (const float*)d_in[19];
  const float* m1W        = (const float*)d_in[20];
  const float* m1b        = (const float*)d_in[21];
  const float* m2W        = (const float*)d_in[22];
  const float* m2b        = (const float*)d_in[23];

  size_t off = 0;
  auto alloc = [&](size_t bytes) -> void* {
    void* p = (char*)d_ws + off; off += (bytes + 255) & ~(size_t)255; return p;
  };
  // chunk-sized staging (max of: call1/3 nk=20480, chunk nk=25600; nb max 1280)
  u16*   kmat  = (u16*)  alloc((size_t)CM * DM * 2);          // 19.7 MB
  u16*   khvh  = (u16*)  alloc((size_t)CM * 2 * DM * 2);      // 39.3 MB
  u16*   qmat  = (u16*)  alloc((size_t)CB * DM * 2);
  float* srcf  = (float*)alloc((size_t)CB * D * 4);
  float* qh    = (float*)alloc((size_t)CB * DM * 4);
  u16*   atto  = (u16*)  alloc((size_t)CB * DM * 2);
  float* fcx   = (float*)alloc((size_t)CB * DM * 4);
  u16*   cat   = (u16*)  alloc((size_t)CB * (DM + D) * 2);
  u16*   h1    = (u16*)  alloc((size_t)CB * D * 2);
  // persistent
  float* n1l1  = (float*)alloc((size_t)BKR * D * 4);          // 10.5 MB
  float* srcl1 = (float*)alloc((size_t)B * D * 4);
  u16*   wkvT  = (u16*)  alloc((size_t)2 * 768 * DM * 2);
  u16*   wqT   = (u16*)  alloc((size_t)2 * DM * DM * 2);
  u16*   fcWT  = (u16*)  alloc((size_t)2 * DM * DM * 2);
  u16*   m1WT  = (u16*)  alloc((size_t)2 * D * (DM + D) * 2);
  u16*   m2WT  = (u16*)  alloc((size_t)2 * D * D * 2);
  float* ztb   = (float*)alloc((size_t)D * 4);
  if (off > ws_size) return;   // diagnostic: fail loudly (absmax) instead of faulting

  // ---- prep: weight transposes to bf16, zt = cos(phase) ----
  zt_kernel<<<1, 128, 0, stream>>>(phase, ztb);
  auto tc = [&](const float* s, u16* dst, int Kd, int Nd) {
    int tot = Kd * Nd;
    tcvt_kernel<<<(tot + 255) / 256, 256, 0, stream>>>(s, dst, Kd, Nd);
  };
  for (int l = 0; l < 2; l++) {
    tc(wk  + (size_t)l * DM * DM, wkvT + (size_t)l * 768 * DM, DM, DM);
    tc(wv  + (size_t)l * DM * DM, wkvT + (size_t)l * 768 * DM + (size_t)DM * DM, DM, DM);
    tc(wq  + (size_t)l * DM * DM, wqT  + (size_t)l * DM * DM, DM, DM);
    tc(fcW + (size_t)l * DM * DM, fcWT + (size_t)l * DM * DM, DM, DM);
    tc(m1W + (size_t)l * (DM + D) * D, m1WT + (size_t)l * D * (DM + D), DM + D, D);
    tc(m2W + (size_t)l * D * D, m2WT + (size_t)l * D * D, D, D);
  }

  auto gemm = [&](const u16* A, const u16* Bt, const float* bias,
                  float* Cf, u16* Cb, int M, int N, int Kd, int relu) {
    dim3 g(M / 128, N / 128);
    gemm_kernel<<<g, 256, 0, stream>>>(A, Bt, bias, Cf, Cb, M, N, Kd, relu);
  };

  // One full attn-agg layer on a (chunk of) rows. All pointers chunk-local.
  auto run_layer = [&](int l, const int* q_nodes, const float* q_feat, int nb,
                       const int* k_nodes, const float* k_feat,
                       const float* t_src, const float* t_ngh, const float* rel,
                       int nk, float* outp) {
    build_q_kernel<<<nb / 2, 256, 0, stream>>>(node_table, q_nodes, q_feat, ztb, qmat, srcf, nb);
    gemm(qmat, wqT + (size_t)l * DM * DM, nullptr, qh, nullptr, nb, DM, DM, 0);
    build_k_kernel<<<nk / 2, 256, 0, stream>>>(node_table, k_nodes, k_feat, t_src, t_ngh, rel,
                                               relW, relb, bfreq, phase, kmat, nk);
    gemm(kmat, wkvT + (size_t)l * 768 * DM, nullptr, nullptr, khvh, nk, 768, DM, 0);
    attn_kernel<<<nb, 64, 0, stream>>>(qh, khvh, k_nodes, atto);
    gemm(atto, fcWT + (size_t)l * DM * DM, nullptr, fcx, nullptr, nb, DM, DM, 0);
    ln_kernel<<<nb / 4, 256, 0, stream>>>(fcx, fcb + l * DM, srcf, ztb, lng + l * DM, lnb + l * DM, cat);
    gemm(cat, m1WT + (size_t)l * D * (DM + D), m1b + l * D, nullptr, h1, nb, D, DM + D, 1);
    gemm(h1, m2WT + (size_t)l * D * D, m2b + l * D, outp, nullptr, nb, D, D, 0);
  };

  // CALL 1: layer 0 on src (nb = B, nk = B*K)
  run_layer(0, src_idx, nullptr, B, n1_nodes, nullptr, cut_time, n1_t, n1_rel, BKR, srcl1);

  // CALL 2: layer 0 on 1-hop neighbors, fully chunked
  for (int c = 0; c < NC; c++) {
    run_layer(0, n1_nodes + (size_t)c * CB, nullptr, CB,
              n2_nodes + (size_t)c * CM, nullptr,
              n1_t + (size_t)c * CB, n2_t + (size_t)c * CM, n2_rel + (size_t)c * CM * 3,
              CM, n1l1 + (size_t)c * CB * D);
  }

  // CALL 3: layer 1 on src (seq feats = n1l1)
  run_layer(1, src_idx, srcl1, B, n1_nodes, n1l1, cut_time, n1_t, n1_rel, BKR, (float*)d_out);
}

// Round 3
// 1891.156 us; speedup vs baseline: 1.2174x; 1.2174x over previous
//
#include <hip/hip_runtime.h>

typedef unsigned int u32;
typedef unsigned short u16;

typedef short bf16x8 __attribute__((ext_vector_type(8)));
typedef float f32x4 __attribute__((ext_vector_type(4)));

#define DD 128
#define DMM 384
#define KNB 20

__device__ __forceinline__ u16 f2b(float f){
  u32 u = __float_as_uint(f);
  u += 0x7fffu + ((u >> 16) & 1u);
  return (u16)(u >> 16);
}
__device__ __forceinline__ float b2f(u32 h){ return __uint_as_float(h << 16); }

// async global->LDS, 16B per lane, dest = wave-uniform base + lane*16
__device__ __forceinline__ void gload16(const void* g, void* l){
  __builtin_amdgcn_global_load_lds((const __attribute__((address_space(1))) void*)g,
                                   (__attribute__((address_space(3))) void*)l, 16, 0, 0);
}

// ---------------- prep ----------------
__global__ void zt_kernel(const float* __restrict__ phase, float* __restrict__ zt){
  int d = threadIdx.x;
  if (d < DD) zt[d] = cosf(phase[d]);
}

// qzt[l][col] = sum_d cos(phase[d]) * wq[l][256+d][col]   (exact fp32)
__global__ void qzt_kernel(const float* __restrict__ wq, const float* __restrict__ phase,
                           float* __restrict__ qzt){
  int idx = blockIdx.x * 128 + threadIdx.x;   // 768 total
  int l = idx / DMM, col = idx % DMM;
  float a = 0.f;
  for (int d = 0; d < DD; d++)
    a += cosf(phase[d]) * wq[(size_t)l * DMM * DMM + (size_t)(256 + d) * DMM + col];
  qzt[idx] = a;
}

// src: K x N row-major fp32  ->  dst: N x K row-major bf16
__global__ void tcvt_kernel(const float* __restrict__ src, u16* __restrict__ dst, int K, int N){
  int i = blockIdx.x * 256 + threadIdx.x;
  if (i >= K * N) return;
  int k = i / N, n = i - k * N;
  dst[(size_t)n * K + k] = f2b(src[i]);
}

// ---------------- merged build: q rows (srcb/srcf) + K rows (kmat) ----------------
__global__ __launch_bounds__(256) void build_kernel(
  const float* __restrict__ node_table,
  const int*   __restrict__ q_nodes, const float* __restrict__ q_feat,
  const int*   __restrict__ k_nodes, const float* __restrict__ k_feat,
  const float* __restrict__ t_src, const float* __restrict__ t_ngh,
  const float* __restrict__ rel,
  const float* __restrict__ relW, const float* __restrict__ relb,
  const float* __restrict__ bfreq, const float* __restrict__ phase,
  u16* __restrict__ srcb, float* __restrict__ srcf, u16* __restrict__ kmat,
  int nb, int nk)
{
  int lr = blockIdx.x * 2 + (threadIdx.x >> 7);
  int d = threadIdx.x & 127;
  if (lr < nb) {
    float s = q_feat ? q_feat[(size_t)lr * DD + d]
                     : node_table[(size_t)q_nodes[lr] * DD + d];
    srcb[(size_t)lr * DD + d] = f2b(s);
    srcf[(size_t)lr * DD + d] = s;
  } else {
    int r = lr - nb;
    if (r >= nk) return;
    int b = r / KNB;
    float f;
    if (k_feat) f = k_feat[(size_t)r * DD + d];
    else { int nd = k_nodes[r]; f = node_table[(size_t)nd * DD + d]; }
    float r0 = rel[(size_t)r * 3 + 0], r1 = rel[(size_t)r * 3 + 1], r2 = rel[(size_t)r * 3 + 2];
    float re = r0 * relW[d] + r1 * relW[DD + d] + r2 * relW[2 * DD + d] + relb[d];
    float dt = t_src[b] - t_ngh[r];
    float te = cosf(dt * bfreq[d] + phase[d]);
    u16* kr = kmat + (size_t)r * DMM;
    kr[d] = f2b(f); kr[DD + d] = f2b(re); kr[2 * DD + d] = f2b(te);
  }
}

// ---------------- GEMM: C[M,N] = A[M,K] @ BT[N,K]^T (bf16, fp32 acc) ----------------
// m97 structure: global_load_lds width-16 staging, BK=64, XOR slot-swizzle on LDS
// (inverse-swizzled global source + swizzled ds_read -> all 8 16B-slots covered).
__global__ __launch_bounds__(256) void gemm_kernel(
  const u16* __restrict__ A, const u16* __restrict__ BT,
  const float* __restrict__ bias,
  float* __restrict__ Cf, u16* __restrict__ Cb,
  int N, int K)
{
  __shared__ __align__(16) u16 As[128 * 64];
  __shared__ __align__(16) u16 Bs[128 * 64];
  int tid = threadIdx.x, lane = tid & 63, w = tid >> 6;
  int wm = w >> 1, wn = w & 1;
  int rr = lane & 15, kq = lane >> 4;
  int crow = lane >> 3;                 // row within 8-row chunk
  int sslot = (lane & 7) ^ crow;        // inverse-swizzled source 16B slot
  const u16* Ab = A + (size_t)(blockIdx.x * 128) * K;
  const u16* Bb = BT + (size_t)(blockIdx.y * 128) * K;
  f32x4 acc[4][4] = {};
  for (int kt = 0; kt < K; kt += 64) {
    __syncthreads();
    #pragma unroll
    for (int cc = 0; cc < 4; cc++) {
      int c = w * 4 + cc;               // 16 chunks of 8 rows each
      gload16(Ab + (size_t)(c * 8 + crow) * K + kt + sslot * 8, &As[c * 512]);
      gload16(Bb + (size_t)(c * 8 + crow) * K + kt + sslot * 8, &Bs[c * 512]);
    }
    __syncthreads();
    #pragma unroll
    for (int ks = 0; ks < 2; ks++) {
      int spb = (ks * 4 + kq) ^ (rr & 7);
      bf16x8 af[4], bf[4];
      #pragma unroll
      for (int i = 0; i < 4; i++) af[i] = *(const bf16x8*)&As[(wm * 64 + i * 16 + rr) * 64 + spb * 8];
      #pragma unroll
      for (int j = 0; j < 4; j++) bf[j] = *(const bf16x8*)&Bs[(wn * 64 + j * 16 + rr) * 64 + spb * 8];
      #pragma unroll
      for (int i = 0; i < 4; i++)
        #pragma unroll
        for (int j = 0; j < 4; j++)
          acc[i][j] = __builtin_amdgcn_mfma_f32_16x16x32_bf16(af[i], bf[j], acc[i][j], 0, 0, 0);
    }
  }
  int drow = lane >> 4, dcol = lane & 15;
  #pragma unroll
  for (int i = 0; i < 4; i++) {
    #pragma unroll
    for (int j = 0; j < 4; j++) {
      int gcol = blockIdx.y * 128 + wn * 64 + j * 16 + dcol;
      float bia = bias ? bias[gcol] : 0.f;
      #pragma unroll
      for (int r = 0; r < 4; r++) {
        int grow = blockIdx.x * 128 + wm * 64 + i * 16 + drow * 4 + r;
        float v = acc[i][j][r] + bia;
        if (Cf) Cf[(size_t)grow * N + gcol] = v;
        else    Cb[(size_t)grow * N + gcol] = f2b(v);
      }
    }
  }
}

// ---------------- attention: one wave per b-row ----------------
__global__ __launch_bounds__(64) void attn_kernel(
  const float* __restrict__ qh,     // nb x 384 fp32
  const u16*  __restrict__ khvh,    // nb*20 x 768 bf16 ([kh|vh])
  const int*  __restrict__ nodes,   // nb*20
  u16* __restrict__ attn_o)         // nb x 384 bf16
{
  int b = blockIdx.x;
  int lane = threadIdx.x;
  int h = lane >> 5, t = lane & 31;
  float qv[6];
  const float* qp = qh + (size_t)b * DMM + h * 192 + t * 6;
  #pragma unroll
  for (int j = 0; j < 6; j++) qv[j] = qp[j];
  __shared__ float sc2[2][KNB];
  const float scale = 0.07216878364870323f;   // 1/sqrt(192)
  for (int n = 0; n < KNB; n++) {
    const u32* kp = (const u32*)(khvh + ((size_t)b * KNB + n) * 768 + h * 192);
    u32 u0 = kp[t * 3 + 0], u1 = kp[t * 3 + 1], u2 = kp[t * 3 + 2];
    float ps = qv[0] * b2f(u0 & 0xffffu) + qv[1] * b2f(u0 >> 16)
             + qv[2] * b2f(u1 & 0xffffu) + qv[3] * b2f(u1 >> 16)
             + qv[4] * b2f(u2 & 0xffffu) + qv[5] * b2f(u2 >> 16);
    ps += __shfl_xor(ps, 1);  ps += __shfl_xor(ps, 2);
    ps += __shfl_xor(ps, 4);  ps += __shfl_xor(ps, 8);  ps += __shfl_xor(ps, 16);
    if (t == 0) sc2[h][n] = ps * scale;
  }
  __syncthreads();
  float s[KNB]; float mx = -3.4e38f;
  #pragma unroll
  for (int n = 0; n < KNB; n++) {
    int nd = nodes[(size_t)b * KNB + n];
    float x = (nd == 0) ? -1e10f : sc2[h][n];
    s[n] = x; mx = fmaxf(mx, x);
  }
  float se = 0.f;
  #pragma unroll
  for (int n = 0; n < KNB; n++) { float e = __expf(s[n] - mx); s[n] = e; se += e; }
  float inv = 1.f / se;
  float a6[6] = {0, 0, 0, 0, 0, 0};
  for (int n = 0; n < KNB; n++) {
    float p = s[n] * inv;
    const u32* vp = (const u32*)(khvh + ((size_t)b * KNB + n) * 768 + DMM);
    u32 u0 = vp[lane * 3 + 0], u1 = vp[lane * 3 + 1], u2 = vp[lane * 3 + 2];
    a6[0] += p * b2f(u0 & 0xffffu); a6[1] += p * b2f(u0 >> 16);
    a6[2] += p * b2f(u1 & 0xffffu); a6[3] += p * b2f(u1 >> 16);
    a6[4] += p * b2f(u2 & 0xffffu); a6[5] += p * b2f(u2 >> 16);
  }
  u16* op = attn_o + (size_t)b * DMM + lane * 6;
  #pragma unroll
  for (int j = 0; j < 6; j++) op[j] = f2b(a6[j]);
}

// ---------------- fused fc-GEMM + residual + LN + concat ----------------
// block = 128 rows x 384 cols, 8 waves (2 row-halves x 4 col-groups of 96)
__global__ __launch_bounds__(512) void fcln_kernel(
  const u16* __restrict__ atto, const u16* __restrict__ fcWT,
  const float* __restrict__ fcb, const float* __restrict__ srcf,
  const float* __restrict__ zt, const float* __restrict__ g,
  const float* __restrict__ bb, u16* __restrict__ cat)
{
  __shared__ __align__(16) u16 As[128 * 64];
  __shared__ __align__(16) u16 Bs[384 * 64];
  __shared__ float rsum[128][4];
  int tid = threadIdx.x, lane = tid & 63, w = tid >> 6;
  int wm = w >> 2, wn = w & 3;
  int rr = lane & 15, kq = lane >> 4;
  int crow = lane >> 3, sslot = (lane & 7) ^ crow;
  int row0 = blockIdx.x * 128;
  const u16* Ab = atto + (size_t)row0 * DMM;
  f32x4 acc[4][6] = {};
  for (int kt = 0; kt < DMM; kt += 64) {
    __syncthreads();
    #pragma unroll
    for (int cc = 0; cc < 2; cc++) {
      int c = w * 2 + cc;
      gload16(Ab + (size_t)(c * 8 + crow) * DMM + kt + sslot * 8, &As[c * 512]);
    }
    #pragma unroll
    for (int cc = 0; cc < 6; cc++) {
      int c = w * 6 + cc;
      gload16(fcWT + (size_t)(c * 8 + crow) * DMM + kt + sslot * 8, &Bs[c * 512]);
    }
    __syncthreads();
    #pragma unroll
    for (int ks = 0; ks < 2; ks++) {
      int spb = (ks * 4 + kq) ^ (rr & 7);
      bf16x8 af[4], bf[6];
      #pragma unroll
      for (int i = 0; i < 4; i++) af[i] = *(const bf16x8*)&As[(wm * 64 + i * 16 + rr) * 64 + spb * 8];
      #pragma unroll
      for (int j = 0; j < 6; j++) bf[j] = *(const bf16x8*)&Bs[(wn * 96 + j * 16 + rr) * 64 + spb * 8];
      #pragma unroll
      for (int i = 0; i < 4; i++)
        #pragma unroll
        for (int j = 0; j < 6; j++)
          acc[i][j] = __builtin_amdgcn_mfma_f32_16x16x32_bf16(af[i], bf[j], acc[i][j], 0, 0, 0);
    }
  }
  int drow = lane >> 4, dcol = lane & 15;
  // add fcb + q residual (q = [src | 0 | zt])
  #pragma unroll
  for (int i = 0; i < 4; i++) {
    #pragma unroll
    for (int j = 0; j < 6; j++) {
      int col = wn * 96 + j * 16 + dcol;
      float fb = fcb[col] + ((col >= 2 * DD) ? zt[col - 2 * DD] : 0.f);
      #pragma unroll
      for (int r = 0; r < 4; r++) {
        int row = row0 + wm * 64 + i * 16 + drow * 4 + r;
        float qv = (col < DD) ? srcf[(size_t)row * DD + col] : 0.f;
        acc[i][j][r] += fb + qv;
      }
    }
  }
  // mean
  float pr[4][4];
  #pragma unroll
  for (int i = 0; i < 4; i++)
    #pragma unroll
    for (int r = 0; r < 4; r++) {
      float s = 0.f;
      #pragma unroll
      for (int j = 0; j < 6; j++) s += acc[i][j][r];
      #pragma unroll
      for (int m = 1; m < 16; m <<= 1) s += __shfl_xor(s, m);
      pr[i][r] = s;
    }
  if ((lane & 15) == 0) {
    #pragma unroll
    for (int i = 0; i < 4; i++)
      #pragma unroll
      for (int r = 0; r < 4; r++)
        rsum[wm * 64 + i * 16 + drow * 4 + r][wn] = pr[i][r];
  }
  __syncthreads();
  float mu[4][4];
  #pragma unroll
  for (int i = 0; i < 4; i++)
    #pragma unroll
    for (int r = 0; r < 4; r++) {
      int R = wm * 64 + i * 16 + drow * 4 + r;
      mu[i][r] = (rsum[R][0] + rsum[R][1] + rsum[R][2] + rsum[R][3]) * (1.f / 384.f);
    }
  __syncthreads();
  // variance
  #pragma unroll
  for (int i = 0; i < 4; i++)
    #pragma unroll
    for (int r = 0; r < 4; r++) {
      float s = 0.f;
      #pragma unroll
      for (int j = 0; j < 6; j++) { float d = acc[i][j][r] - mu[i][r]; s += d * d; }
      #pragma unroll
      for (int m = 1; m < 16; m <<= 1) s += __shfl_xor(s, m);
      pr[i][r] = s;
    }
  if ((lane & 15) == 0) {
    #pragma unroll
    for (int i = 0; i < 4; i++)
      #pragma unroll
      for (int r = 0; r < 4; r++)
        rsum[wm * 64 + i * 16 + drow * 4 + r][wn] = pr[i][r];
  }
  __syncthreads();
  float rstd[4][4];
  #pragma unroll
  for (int i = 0; i < 4; i++)
    #pragma unroll
    for (int r = 0; r < 4; r++) {
      int R = wm * 64 + i * 16 + drow * 4 + r;
      float vv = (rsum[R][0] + rsum[R][1] + rsum[R][2] + rsum[R][3]) * (1.f / 384.f);
      rstd[i][r] = rsqrtf(vv + 1e-5f);
    }
  // write LN cols
  #pragma unroll
  for (int i = 0; i < 4; i++)
    #pragma unroll
    for (int j = 0; j < 6; j++) {
      int col = wn * 96 + j * 16 + dcol;
      float gg = g[col], bbb = bb[col];
      #pragma unroll
      for (int r = 0; r < 4; r++) {
        int row = row0 + wm * 64 + i * 16 + drow * 4 + r;
        float val = (acc[i][j][r] - mu[i][r]) * rstd[i][r] * gg + bbb;
        cat[(size_t)row * 512 + col] = f2b(val);
      }
    }
  // copy src into cols 384..511
  for (int e = tid; e < 128 * DD; e += 512) {
    int r2 = e >> 7, c2 = e & 127;
    cat[(size_t)(row0 + r2) * 512 + DMM + c2] = f2b(srcf[(size_t)(row0 + r2) * DD + c2]);
  }
}

// ---------------- fused mg: out = relu(cat@m1W + m1b) @ m2W + m2b ----------------
__global__ __launch_bounds__(256) void mg_kernel(
  const u16* __restrict__ cat, const u16* __restrict__ m1WT, const float* __restrict__ m1b,
  const u16* __restrict__ m2WT, const float* __restrict__ m2b,
  float* __restrict__ out)
{
  __shared__ __align__(16) u16 As[128 * 64];
  __shared__ __align__(16) u16 Bs[128 * 64];
  __shared__ __align__(16) u16 Hs[128 * 128];
  int tid = threadIdx.x, lane = tid & 63, w = tid >> 6;
  int wm = w >> 1, wn = w & 1;
  int rr = lane & 15, kq = lane >> 4;
  int crow = lane >> 3, sslot = (lane & 7) ^ crow;
  int row0 = blockIdx.x * 128;
  const u16* Ab = cat + (size_t)row0 * 512;
  f32x4 acc[4][4] = {};
  // phase 1: h = relu(cat @ m1WT^T + m1b), K=512
  for (int kt = 0; kt < 512; kt += 64) {
    __syncthreads();
    #pragma unroll
    for (int cc = 0; cc < 4; cc++) {
      int c = w * 4 + cc;
      gload16(Ab + (size_t)(c * 8 + crow) * 512 + kt + sslot * 8, &As[c * 512]);
      gload16(m1WT + (size_t)(c * 8 + crow) * 512 + kt + sslot * 8, &Bs[c * 512]);
    }
    __syncthreads();
    #pragma unroll
    for (int ks = 0; ks < 2; ks++) {
      int spb = (ks * 4 + kq) ^ (rr & 7);
      bf16x8 af[4], bf[4];
      #pragma unroll
      for (int i = 0; i < 4; i++) af[i] = *(const bf16x8*)&As[(wm * 64 + i * 16 + rr) * 64 + spb * 8];
      #pragma unroll
      for (int j = 0; j < 4; j++) bf[j] = *(const bf16x8*)&Bs[(wn * 64 + j * 16 + rr) * 64 + spb * 8];
      #pragma unroll
      for (int i = 0; i < 4; i++)
        #pragma unroll
        for (int j = 0; j < 4; j++)
          acc[i][j] = __builtin_amdgcn_mfma_f32_16x16x32_bf16(af[i], bf[j], acc[i][j], 0, 0, 0);
    }
  }
  int drow = lane >> 4, dcol = lane & 15;
  __syncthreads();   // phase-1 LDS reads done before Hs writes / Bs re-stage
  #pragma unroll
  for (int i = 0; i < 4; i++)
    #pragma unroll
    for (int j = 0; j < 4; j++) {
      int col = wn * 64 + j * 16 + dcol;
      float mb = m1b[col];
      #pragma unroll
      for (int r = 0; r < 4; r++) {
        int row = wm * 64 + i * 16 + drow * 4 + r;
        float v = fmaxf(acc[i][j][r] + mb, 0.f);
        Hs[row * 128 + (((col >> 3) ^ (row & 7)) << 3) + (col & 7)] = f2b(v);
      }
    }
  // phase 2: out = h @ m2WT^T + m2b, K=128
  f32x4 acc2[4][4] = {};
  for (int kt = 0; kt < 128; kt += 64) {
    #pragma unroll
    for (int cc = 0; cc < 4; cc++) {
      int c = w * 4 + cc;
      gload16(m2WT + (size_t)(c * 8 + crow) * 128 + kt + sslot * 8, &Bs[c * 512]);
    }
    __syncthreads();
    #pragma unroll
    for (int ks = 0; ks < 2; ks++) {
      int spb = (ks * 4 + kq) ^ (rr & 7);
      int slh = ((kt >> 3) + ks * 4 + kq) ^ (rr & 7);
      bf16x8 af[4], bf[4];
      #pragma unroll
      for (int i = 0; i < 4; i++) af[i] = *(const bf16x8*)&Hs[(wm * 64 + i * 16 + rr) * 128 + slh * 8];
      #pragma unroll
      for (int j = 0; j < 4; j++) bf[j] = *(const bf16x8*)&Bs[(wn * 64 + j * 16 + rr) * 64 + spb * 8];
      #pragma unroll
      for (int i = 0; i < 4; i++)
        #pragma unroll
        for (int j = 0; j < 4; j++)
          acc2[i][j] = __builtin_amdgcn_mfma_f32_16x16x32_bf16(af[i], bf[j], acc2[i][j], 0, 0, 0);
    }
    __syncthreads();
  }
  #pragma unroll
  for (int i = 0; i < 4; i++)
    #pragma unroll
    for (int j = 0; j < 4; j++) {
      int col = wn * 64 + j * 16 + dcol;
      float mb = m2b[col];
      #pragma unroll
      for (int r = 0; r < 4; r++) {
        int row = row0 + wm * 64 + i * 16 + drow * 4 + r;
        out[(size_t)row * DD + col] = acc2[i][j][r] + mb;
      }
    }
}

extern "C" void kernel_launch(void* const* d_in, const int* in_sizes, int n_in,
                              void* d_out, int out_size, void* d_ws, size_t ws_size,
                              hipStream_t stream)
{
  (void)in_sizes; (void)n_in; (void)out_size;
  const int B = 1024, K = 20, D = 128, DM = 384;
  const int BKR = B * K;                 // 20480
  const int NC = 16, CB = BKR / NC;      // 1280 b-rows per chunk
  const int CM = CB * K;                 // 25600 k-rows per chunk

  const int*   src_idx    = (const int*)  d_in[0];
  const float* cut_time   = (const float*)d_in[1];
  const int*   n1_nodes   = (const int*)  d_in[2];
  const float* n1_t       = (const float*)d_in[3];
  const float* n1_rel     = (const float*)d_in[4];
  const int*   n2_nodes   = (const int*)  d_in[5];
  const float* n2_t       = (const float*)d_in[6];
  const float* n2_rel     = (const float*)d_in[7];
  const float* node_table = (const float*)d_in[8];
  const float* bfreq      = (const float*)d_in[9];
  const float* phase      = (const float*)d_in[10];
  const float* relW       = (const float*)d_in[11];
  const float* relb       = (const float*)d_in[12];
  const float* wq         = (const float*)d_in[13];
  const float* wk         = (const float*)d_in[14];
  const float* wv         = (const float*)d_in[15];
  const float* fcW        = (const float*)d_in[16];
  const float* fcb        = (const float*)d_in[17];
  const float* lng        = (const float*)d_in[18];
  const float* lnb        = (const float*)d_in[19];
  const float* m1W        = (const float*)d_in[20];
  const float* m1b        = (const float*)d_in[21];
  const float* m2W        = (const float*)d_in[22];
  const float* m2b        = (const float*)d_in[23];

  size_t off = 0;
  auto alloc = [&](size_t bytes) -> void* {
    void* p = (char*)d_ws + off; off += (bytes + 255) & ~(size_t)255; return p;
  };
  u16*   kmat  = (u16*)  alloc((size_t)CM * DM * 2);          // 19.7 MB
  u16*   khvh  = (u16*)  alloc((size_t)CM * 2 * DM * 2);      // 39.3 MB
  u16*   srcb  = (u16*)  alloc((size_t)CB * D * 2);
  float* srcf  = (float*)alloc((size_t)CB * D * 4);
  float* qh    = (float*)alloc((size_t)CB * DM * 4);
  u16*   atto  = (u16*)  alloc((size_t)CB * DM * 2);
  u16*   cat   = (u16*)  alloc((size_t)CB * (DM + D) * 2);
  float* n1l1  = (float*)alloc((size_t)BKR * D * 4);          // 10.5 MB
  float* srcl1 = (float*)alloc((size_t)B * D * 4);
  u16*   wkvT  = (u16*)  alloc((size_t)2 * 768 * DM * 2);
  u16*   wqTT  = (u16*)  alloc((size_t)2 * DM * D * 2);       // wq top-128 rows, transposed
  u16*   fcWT  = (u16*)  alloc((size_t)2 * DM * DM * 2);
  u16*   m1WT  = (u16*)  alloc((size_t)2 * D * (DM + D) * 2);
  u16*   m2WT  = (u16*)  alloc((size_t)2 * D * D * 2);
  float* qzt   = (float*)alloc((size_t)2 * DM * 4);
  float* ztb   = (float*)alloc((size_t)D * 4);
  if (off > ws_size) return;   // fail loudly (absmax) instead of faulting

  // ---- prep ----
  zt_kernel<<<1, 128, 0, stream>>>(phase, ztb);
  qzt_kernel<<<6, 128, 0, stream>>>(wq, phase, qzt);
  auto tc = [&](const float* s, u16* dst, int Kd, int Nd) {
    int tot = Kd * Nd;
    tcvt_kernel<<<(tot + 255) / 256, 256, 0, stream>>>(s, dst, Kd, Nd);
  };
  for (int l = 0; l < 2; l++) {
    tc(wk  + (size_t)l * DM * DM, wkvT + (size_t)l * 768 * DM, DM, DM);
    tc(wv  + (size_t)l * DM * DM, wkvT + (size_t)l * 768 * DM + (size_t)DM * DM, DM, DM);
    tc(wq  + (size_t)l * DM * DM, wqTT + (size_t)l * DM * D, D, DM);   // top 128 rows only
    tc(fcW + (size_t)l * DM * DM, fcWT + (size_t)l * DM * DM, DM, DM);
    tc(m1W + (size_t)l * (DM + D) * D, m1WT + (size_t)l * D * (DM + D), DM + D, D);
    tc(m2W + (size_t)l * D * D, m2WT + (size_t)l * D * D, D, D);
  }

  // One full attn-agg layer on (a chunk of) rows; all pointers chunk-local.
  auto run_layer = [&](int l, const int* q_nodes, const float* q_feat, int nb,
                       const int* k_nodes, const float* k_feat,
                       const float* t_src, const float* t_ngh, const float* rel,
                       int nk, float* outp) {
    build_kernel<<<(nb + nk) / 2, 256, 0, stream>>>(
        node_table, q_nodes, q_feat, k_nodes, k_feat, t_src, t_ngh, rel,
        relW, relb, bfreq, phase, srcb, srcf, kmat, nb, nk);
    {   // qh = srcb @ wqTT^T + qzt   (M=nb, N=384, K=128)
      dim3 g(nb / 128, 3);
      gemm_kernel<<<g, 256, 0, stream>>>(srcb, wqTT + (size_t)l * DM * D,
                                         qzt + (size_t)l * DM, qh, nullptr, DM, D);
    }
    {   // khvh = kmat @ wkvT^T      (M=nk, N=768, K=384)
      dim3 g(nk / 128, 6);
      gemm_kernel<<<g, 256, 0, stream>>>(kmat, wkvT + (size_t)l * 768 * DM,
                                         nullptr, nullptr, khvh, 768, DM);
    }
    attn_kernel<<<nb, 64, 0, stream>>>(qh, khvh, k_nodes, atto);
    fcln_kernel<<<nb / 128, 512, 0, stream>>>(atto, fcWT + (size_t)l * DM * DM,
                                              fcb + l * DM, srcf, ztb,
                                              lng + l * DM, lnb + l * DM, cat);
    mg_kernel<<<nb / 128, 256, 0, stream>>>(cat, m1WT + (size_t)l * D * (DM + D),
                                            m1b + l * D, m2WT + (size_t)l * D * D,
                                            m2b + l * D, outp);
  };

  // CALL 1: layer 0 on src (nb = B, nk = B*K)
  run_layer(0, src_idx, nullptr, B, n1_nodes, nullptr, cut_time, n1_t, n1_rel, BKR, srcl1);

  // CALL 2: layer 0 on 1-hop neighbors, fully chunked
  for (int c = 0; c < NC; c++) {
    run_layer(0, n1_nodes + (size_t)c * CB, nullptr, CB,
              n2_nodes + (size_t)c * CM, nullptr,
              n1_t + (size_t)c * CB, n2_t + (size_t)c * CM, n2_rel + (size_t)c * CM * 3,
              CM, n1l1 + (size_t)c * CB * D);
  }

  // CALL 3: layer 1 on src (seq feats = n1l1)
  run_layer(1, src_idx, srcl1, B, n1_nodes, n1l1, cut_time, n1_t, n1_rel, BKR, (float*)d_out);
}